// Round 5
// baseline (159.113 us; speedup 1.0000x reference)
//
#include <hip/hip_runtime.h>
#include <math.h>

// knnLoss: B=4, N=8192, k=3. LDS-free 3-NN: targets pre-packed to global,
// read as wave-uniform VMEM broadcasts (L1-resident); pk_fma dual-fp32 math.
#define BATCH 4
#define NPTS 8192
#define TILE 512            // targets per block chunk (16 KB packed, fits L1)
#define TSPLIT 16           // NPTS / TILE
#define SRC_PER_THREAD 4
#define SRC_PER_BLOCK 1024  // 256 threads x 4 sources
#define SRC_CHUNKS 8        // NPTS / SRC_PER_BLOCK
#define NSRC_TOT (BATCH * NPTS)  // 32768
#define NGROUP (BATCH * NPTS / 2)  // 16384 target pair-groups

typedef __attribute__((ext_vector_type(2))) float f2;
typedef __attribute__((ext_vector_type(4))) float f4;

__device__ __forceinline__ f2 pk_fma(f2 a, f2 b, f2 c) {
    f2 d;
    asm("v_pk_fma_f32 %0, %1, %2, %3" : "=v"(d) : "v"(a), "v"(b), "v"(c));
    return d;
}

// Branchless insert into sorted ascending triple; 4 ops via med3.
__device__ __forceinline__ void insert3(float d, float& a0, float& a1, float& a2) {
    float h = fmaxf(a1, d);
    float m = __builtin_amdgcn_fmed3f(a0, a1, d);
    a2 = fminf(a2, h);
    a1 = m;
    a0 = fminf(a0, d);
}

// Merge two sorted triples -> sorted 3 smallest of union. 6 ops.
__device__ __forceinline__ void merge33(float a0, float a1, float a2,
                                        float& b0, float& b1, float& b2) {
    float s0 = fminf(a0, b0);
    float h  = fmaxf(a0, b0);
    float m  = fminf(a1, b1);
    float mm = fminf(a2, b2);
    b1 = fminf(h, m);
    b2 = __builtin_amdgcn_fmed3f(h, m, mm);
    b0 = s0;
}

// Pack target pairs: group g (targets 2g,2g+1) -> tp[2g]={x0,x1,y0,y1},
// tp[2g+1]={z0,z1,w0,w1}, w=|t|^2/2 (1e38 sentinel for (0,0,0) points).
__global__ __launch_bounds__(256) void knn_prep(const float* __restrict__ tgt,
                                                f4* __restrict__ tp,
                                                float* __restrict__ hdr) {
    int g = blockIdx.x * 256 + threadIdx.x;  // 0 .. NGROUP-1
    if (g < 16) hdr[g] = 0.0f;               // zero acc/cnt/ticket header
    const float* tb = tgt + (size_t)g * 6;
    float x0 = tb[0], y0 = tb[1], z0 = tb[2];
    float x1 = tb[3], y1 = tb[4], z1 = tb[5];
    float w0 = 0.5f * (x0 * x0 + y0 * y0 + z0 * z0);
    float w1 = 0.5f * (x1 * x1 + y1 * y1 + z1 * z1);
    if (!(x0 != 0.f || y0 != 0.f || z0 != 0.f)) w0 = 1.0e38f;
    if (!(x1 != 0.f || y1 != 0.f || z1 != 0.f)) w1 = 1.0e38f;
    tp[2 * (size_t)g + 0] = (f4){x0, x1, y0, y1};
    tp[2 * (size_t)g + 1] = (f4){z0, z1, w0, w1};
}

__global__ __launch_bounds__(256) void knn_partial(const float* __restrict__ src,
                                                   const f4* __restrict__ tp,
                                                   float* __restrict__ part) {
    const int tid = threadIdx.x;
    const int sc = blockIdx.x, tc = blockIdx.y, b = blockIdx.z;
    // Divergent-typed zero: keeps the uniform target loads on the VMEM path
    // (prevents scalarization to s_load, whose OOO returns force lgkmcnt(0)).
    int dv = __builtin_amdgcn_mbcnt_lo(0u, 0u);

    // 4 sources per thread; -s duplicated in both packed halves.
    f2 nx[SRC_PER_THREAD], ny[SRC_PER_THREAD], nz[SRC_PER_THREAD];
    #pragma unroll
    for (int s = 0; s < SRC_PER_THREAD; ++s) {
        int i = sc * SRC_PER_BLOCK + tid + 256 * s;
        const float* sp = src + ((size_t)b * NPTS + i) * 3;
        float ax = sp[0], ay = sp[1], az = sp[2];
        nx[s] = (f2){-ax, -ax};
        ny[s] = (f2){-ay, -ay};
        nz[s] = (f2){-az, -az};
    }

    // 8 independent chains: [source][even/odd target], v-domain (v = t^2/2 - s.t).
    float c0[SRC_PER_THREAD][2], c1[SRC_PER_THREAD][2], c2[SRC_PER_THREAD][2];
    #pragma unroll
    for (int s = 0; s < SRC_PER_THREAD; ++s)
        for (int h = 0; h < 2; ++h) { c0[s][h] = c1[s][h] = c2[s][h] = 3e38f; }

    const f4* tbase = tp + ((size_t)b * (NPTS / 2) + (size_t)tc * (TILE / 2)) * 2 + dv;

    #pragma unroll 8
    for (int e = 0; e < TILE / 2; ++e) {
        f4 p = tbase[2 * e + 0];   // global_load_dwordx4, uniform addr (L1 broadcast)
        f4 q = tbase[2 * e + 1];
        f2 xs = __builtin_shufflevector(p, p, 0, 1);
        f2 ys = __builtin_shufflevector(p, p, 2, 3);
        f2 zs = __builtin_shufflevector(q, q, 0, 1);
        f2 wh = __builtin_shufflevector(q, q, 2, 3);
        #pragma unroll
        for (int s = 0; s < SRC_PER_THREAD; ++s) {
            f2 v = pk_fma(xs, nx[s], wh);
            v = pk_fma(ys, ny[s], v);
            v = pk_fma(zs, nz[s], v);
            insert3(v.x, c0[s][0], c1[s][0], c2[s][0]);
            insert3(v.y, c0[s][1], c1[s][1], c2[s][1]);
        }
    }

    #pragma unroll
    for (int s = 0; s < SRC_PER_THREAD; ++s) {
        merge33(c0[s][1], c1[s][1], c2[s][1], c0[s][0], c1[s][0], c2[s][0]);
        size_t flat = (size_t)b * NPTS + sc * SRC_PER_BLOCK + tid + 256 * s;
        part[((size_t)tc * 3 + 0) * NSRC_TOT + flat] = c0[s][0];
        part[((size_t)tc * 3 + 1) * NSRC_TOT + flat] = c1[s][0];
        part[((size_t)tc * 3 + 2) * NSRC_TOT + flat] = c2[s][0];
    }
}

__global__ __launch_bounds__(128) void knn_merge(const float* __restrict__ src,
                                                 const float* __restrict__ part,
                                                 float* __restrict__ acc,
                                                 float* __restrict__ cnt,
                                                 unsigned* __restrict__ ticket,
                                                 float* __restrict__ out) {
    const int gid = blockIdx.x * 128 + threadIdx.x;  // 0 .. NSRC_TOT-1
    const int b = gid >> 13;

    // 48 v-values -> 4 independent sub-triples (ILP), then merge tree.
    float t0[4], t1[4], t2[4];
    #pragma unroll
    for (int c = 0; c < 4; ++c) { t0[c] = t1[c] = t2[c] = 3e38f; }
    #pragma unroll
    for (int q = 0; q < TSPLIT * 3; ++q)
        insert3(part[(size_t)q * NSRC_TOT + gid], t0[q & 3], t1[q & 3], t2[q & 3]);
    merge33(t0[1], t1[1], t2[1], t0[0], t1[0], t2[0]);
    merge33(t0[3], t1[3], t2[3], t0[2], t1[2], t2[2]);
    merge33(t0[2], t1[2], t2[2], t0[0], t1[0], t2[0]);

    float sx = src[(size_t)gid * 3 + 0];
    float sy = src[(size_t)gid * 3 + 1];
    float sz = src[(size_t)gid * 3 + 2];
    float s2 = sx * sx + sy * sy + sz * sz;
    bool valid = (sx != 0.f) || (sy != 0.f) || (sz != 0.f);
    // Reconstruct d^2 = 2v + s^2, clamp, sqrt.
    float d0 = sqrtf(fmaxf(fmaf(2.f, t0[0], s2), 0.f));
    float d1 = sqrtf(fmaxf(fmaf(2.f, t1[0], s2), 0.f));
    float d2 = sqrtf(fmaxf(fmaf(2.f, t2[0], s2), 0.f));
    float s = valid ? (d0 + d1 + d2) : 0.f;
    float c = valid ? 1.f : 0.f;

    for (int off = 32; off >= 1; off >>= 1) {
        s += __shfl_down(s, off);
        c += __shfl_down(c, off);
    }
    __shared__ float red_s[2], red_c[2];
    int wave = threadIdx.x >> 6, lane = threadIdx.x & 63;
    if (lane == 0) { red_s[wave] = s; red_c[wave] = c; }
    __syncthreads();
    if (threadIdx.x == 0) {
        atomicAdd(&acc[b], red_s[0] + red_s[1]);
        atomicAdd(&cnt[b], red_c[0] + red_c[1]);
        __threadfence();
        unsigned t = atomicAdd(ticket, 1u);
        if (t == (unsigned)(gridDim.x - 1)) {
            float loss = 0.f;
            #pragma unroll
            for (int bb = 0; bb < BATCH; ++bb) {
                float as = atomicAdd(&acc[bb], 0.f);
                float ac = atomicAdd(&cnt[bb], 0.f);
                loss += as / (ac * 3.0f);
            }
            out[0] = loss * (1.0f / BATCH);
        }
    }
}

extern "C" void kernel_launch(void* const* d_in, const int* in_sizes, int n_in,
                              void* d_out, int out_size, void* d_ws, size_t ws_size,
                              hipStream_t stream) {
    const float* src = (const float*)d_in[0];
    const float* tgt = (const float*)d_in[1];
    float* out = (float*)d_out;

    // ws: [0,16) acc[4]; [16,32) cnt[4]; [32,36) ticket; [256, 256+512K) packed
    // targets; [1M, 1M+6.3M) partials
    float* hdr = (float*)d_ws;
    float* acc = hdr;
    float* cnt = hdr + 4;
    unsigned* ticket = (unsigned*)((char*)d_ws + 32);
    f4* tp = (f4*)((char*)d_ws + 256);                    // 16384*2*16 B = 512 KB
    float* part = (float*)((char*)d_ws + (1u << 20));     // 16*3*32768*4 B = 6.29 MB

    knn_prep<<<dim3(NGROUP / 256), 256, 0, stream>>>(tgt, tp, hdr);

    dim3 g1(SRC_CHUNKS, TSPLIT, BATCH);  // 8 x 16 x 4 = 512 blocks
    knn_partial<<<g1, 256, 0, stream>>>(src, tp, part);

    knn_merge<<<dim3(NSRC_TOT / 128), 128, 0, stream>>>(src, part, acc, cnt, ticket, out);
}

// Round 6
// 121.978 us; speedup vs baseline: 1.3044x; 1.3044x over previous
//
#include <hip/hip_runtime.h>
#include <math.h>

// knnLoss: B=4, N=8192, k=3. LDS tiles + register-prefetch pipeline,
// pk_fma dual-fp32 distance (v-domain), max-occupancy grid.
#define BATCH 4
#define NPTS 8192
#define NSRC_TOT (BATCH * NPTS)  // 32768

typedef __attribute__((ext_vector_type(2))) float f2;
typedef __attribute__((ext_vector_type(4))) float f4;

__device__ __forceinline__ f2 pk_fma(f2 a, f2 b, f2 c) {
    f2 d;
    asm("v_pk_fma_f32 %0, %1, %2, %3" : "=v"(d) : "v"(a), "v"(b), "v"(c));
    return d;
}

// Branchless insert into sorted ascending triple; 4 ops via med3.
__device__ __forceinline__ void insert3(float d, float& a0, float& a1, float& a2) {
    float h = fmaxf(a1, d);
    float m = __builtin_amdgcn_fmed3f(a0, a1, d);
    a2 = fminf(a2, h);
    a1 = m;
    a0 = fminf(a0, d);
}

// Merge two sorted triples -> sorted 3 smallest of union. 6 ops.
__device__ __forceinline__ void merge33(float a0, float a1, float a2,
                                        float& b0, float& b1, float& b2) {
    float s0 = fminf(a0, b0);
    float h  = fmaxf(a0, b0);
    float m  = fminf(a1, b1);
    float mm = fminf(a2, b2);
    b1 = fminf(h, m);
    b2 = __builtin_amdgcn_fmed3f(h, m, mm);
    b0 = s0;
}

// grid: (SRC_CHUNKS, TSPLIT, BATCH); 256 threads, 2 sources/thread.
template <int TSPLITT, int TILET>
__global__ __launch_bounds__(256, 6)
void knn_partial(const float* __restrict__ src, const float* __restrict__ tgt,
                 float* __restrict__ part, float* __restrict__ hdr) {
    constexpr int ENTRIES = TILET / 2;
    __shared__ f4 ts[ENTRIES * 2];
    const int tid = threadIdx.x;
    const int sc = blockIdx.x, tc = blockIdx.y, b = blockIdx.z;

    // Zero the 64-byte reduction header once (merge runs strictly after).
    if (sc == 0 && tc == 0 && b == 0 && tid < 16) hdr[tid] = 0.0f;

    // Stage: entry e = targets 2e,2e+1 -> {x0,x1,y0,y1},{z0,z1,w0,w1},
    // w = |t|^2/2 (1e38 sentinel for (0,0,0) targets).
    for (int e = tid; e < ENTRIES; e += 256) {
        const float* tb = tgt + ((size_t)b * NPTS + (size_t)tc * TILET + 2 * e) * 3;
        float x0 = tb[0], y0 = tb[1], z0 = tb[2];
        float x1 = tb[3], y1 = tb[4], z1 = tb[5];
        float w0 = 0.5f * (x0 * x0 + y0 * y0 + z0 * z0);
        float w1 = 0.5f * (x1 * x1 + y1 * y1 + z1 * z1);
        if (!(x0 != 0.f || y0 != 0.f || z0 != 0.f)) w0 = 1.0e38f;
        if (!(x1 != 0.f || y1 != 0.f || z1 != 0.f)) w1 = 1.0e38f;
        ts[2 * e + 0] = (f4){x0, x1, y0, y1};
        ts[2 * e + 1] = (f4){z0, z1, w0, w1};
    }
    __syncthreads();

    // 2 sources/thread; -s duplicated in both packed halves.
    const int src_per_block = 512;
    f2 nx[2], ny[2], nz[2];
    #pragma unroll
    for (int s = 0; s < 2; ++s) {
        int i = sc * src_per_block + tid + 256 * s;
        const float* sp = src + ((size_t)b * NPTS + i) * 3;
        float ax = sp[0], ay = sp[1], az = sp[2];
        nx[s] = (f2){-ax, -ax};
        ny[s] = (f2){-ay, -ay};
        nz[s] = (f2){-az, -az};
    }

    // 4 independent chains: [source][even/odd target], v = t^2/2 - s.t.
    float c0[2][2], c1[2][2], c2[2][2];
    #pragma unroll
    for (int s = 0; s < 2; ++s)
        for (int h = 0; h < 2; ++h) { c0[s][h] = c1[s][h] = c2[s][h] = 3e38f; }

    // Register-prefetch pipeline: load e+1 while computing e.
    f4 p = ts[0], q = ts[1];
    #pragma unroll 4
    for (int e = 0; e < ENTRIES; ++e) {
        f4 pn, qn;
        if (e + 1 < ENTRIES) {
            pn = ts[2 * e + 2];
            qn = ts[2 * e + 3];
        }
        f2 xs = __builtin_shufflevector(p, p, 0, 1);
        f2 ys = __builtin_shufflevector(p, p, 2, 3);
        f2 zs = __builtin_shufflevector(q, q, 0, 1);
        f2 wh = __builtin_shufflevector(q, q, 2, 3);
        #pragma unroll
        for (int s = 0; s < 2; ++s) {
            f2 v = pk_fma(xs, nx[s], wh);
            v = pk_fma(ys, ny[s], v);
            v = pk_fma(zs, nz[s], v);
            insert3(v.x, c0[s][0], c1[s][0], c2[s][0]);
            insert3(v.y, c0[s][1], c1[s][1], c2[s][1]);
        }
        p = pn;
        q = qn;
    }

    #pragma unroll
    for (int s = 0; s < 2; ++s) {
        merge33(c0[s][1], c1[s][1], c2[s][1], c0[s][0], c1[s][0], c2[s][0]);
        size_t flat = (size_t)b * NPTS + sc * src_per_block + tid + 256 * s;
        part[((size_t)tc * 3 + 0) * NSRC_TOT + flat] = c0[s][0];
        part[((size_t)tc * 3 + 1) * NSRC_TOT + flat] = c1[s][0];
        part[((size_t)tc * 3 + 2) * NSRC_TOT + flat] = c2[s][0];
    }
}

template <int TSPLITT>
__global__ __launch_bounds__(256)
void knn_merge(const float* __restrict__ src, const float* __restrict__ part,
               float* __restrict__ acc, float* __restrict__ cnt,
               unsigned* __restrict__ ticket, float* __restrict__ out) {
    const int gid = blockIdx.x * 256 + threadIdx.x;  // 0 .. NSRC_TOT-1
    const int b = gid >> 13;

    // TSPLITT*3 v-values -> 8 independent sub-triples (ILP), then merge tree.
    float t0[8], t1[8], t2[8];
    #pragma unroll
    for (int c = 0; c < 8; ++c) { t0[c] = t1[c] = t2[c] = 3e38f; }
    #pragma unroll
    for (int q = 0; q < TSPLITT * 3; ++q)
        insert3(part[(size_t)q * NSRC_TOT + gid], t0[q & 7], t1[q & 7], t2[q & 7]);
    merge33(t0[1], t1[1], t2[1], t0[0], t1[0], t2[0]);
    merge33(t0[3], t1[3], t2[3], t0[2], t1[2], t2[2]);
    merge33(t0[5], t1[5], t2[5], t0[4], t1[4], t2[4]);
    merge33(t0[7], t1[7], t2[7], t0[6], t1[6], t2[6]);
    merge33(t0[2], t1[2], t2[2], t0[0], t1[0], t2[0]);
    merge33(t0[6], t1[6], t2[6], t0[4], t1[4], t2[4]);
    merge33(t0[4], t1[4], t2[4], t0[0], t1[0], t2[0]);

    float sx = src[(size_t)gid * 3 + 0];
    float sy = src[(size_t)gid * 3 + 1];
    float sz = src[(size_t)gid * 3 + 2];
    float s2 = sx * sx + sy * sy + sz * sz;
    bool valid = (sx != 0.f) || (sy != 0.f) || (sz != 0.f);
    // Reconstruct d^2 = 2v + s^2, clamp, sqrt.
    float d0 = sqrtf(fmaxf(fmaf(2.f, t0[0], s2), 0.f));
    float d1 = sqrtf(fmaxf(fmaf(2.f, t1[0], s2), 0.f));
    float d2 = sqrtf(fmaxf(fmaf(2.f, t2[0], s2), 0.f));
    float s = valid ? (d0 + d1 + d2) : 0.f;
    float c = valid ? 1.f : 0.f;

    for (int off = 32; off >= 1; off >>= 1) {
        s += __shfl_down(s, off);
        c += __shfl_down(c, off);
    }
    __shared__ float red_s[4], red_c[4];
    int wave = threadIdx.x >> 6, lane = threadIdx.x & 63;
    if (lane == 0) { red_s[wave] = s; red_c[wave] = c; }
    __syncthreads();
    if (threadIdx.x == 0) {
        atomicAdd(&acc[b], red_s[0] + red_s[1] + red_s[2] + red_s[3]);
        atomicAdd(&cnt[b], red_c[0] + red_c[1] + red_c[2] + red_c[3]);
        __threadfence();
        unsigned t = atomicAdd(ticket, 1u);
        if (t == (unsigned)(gridDim.x - 1)) {
            float loss = 0.f;
            #pragma unroll
            for (int bb = 0; bb < BATCH; ++bb) {
                float as = atomicAdd(&acc[bb], 0.f);
                float ac = atomicAdd(&cnt[bb], 0.f);
                loss += as / (ac * 3.0f);
            }
            out[0] = loss * (1.0f / BATCH);
        }
    }
}

extern "C" void kernel_launch(void* const* d_in, const int* in_sizes, int n_in,
                              void* d_out, int out_size, void* d_ws, size_t ws_size,
                              hipStream_t stream) {
    const float* src = (const float*)d_in[0];
    const float* tgt = (const float*)d_in[1];
    float* out = (float*)d_out;

    // ws: [0,16) acc[4]; [16,32) cnt[4]; [32,36) ticket; [1M, ...) partials
    float* hdr = (float*)d_ws;
    float* acc = hdr;
    float* cnt = hdr + 4;
    unsigned* ticket = (unsigned*)((char*)d_ws + 32);
    float* part = (float*)((char*)d_ws + (1u << 20));

    // TSPLIT=32 needs 1M + 32*3*32768*4 = 13.6 MB of ws; else fall back.
    if (ws_size >= (size_t)(14u << 20)) {
        dim3 g1(16, 32, BATCH);  // 2048 blocks, TILE=256, 4 KB LDS, 32 waves/CU
        knn_partial<32, 256><<<g1, 256, 0, stream>>>(src, tgt, part, hdr);
        knn_merge<32><<<dim3(NSRC_TOT / 256), 256, 0, stream>>>(src, part, acc, cnt,
                                                                ticket, out);
    } else {
        dim3 g1(16, 16, BATCH);  // 1024 blocks, TILE=512, 8 KB LDS
        knn_partial<16, 512><<<g1, 256, 0, stream>>>(src, tgt, part, hdr);
        knn_merge<16><<<dim3(NSRC_TOT / 256), 256, 0, stream>>>(src, part, acc, cnt,
                                                                ticket, out);
    }
}